// Round 6
// baseline (95.374 us; speedup 1.0000x reference)
//
#include <hip/hip_runtime.h>

#define MARGIN 0.2f
#define EPSC 1e-6f
#define FLAG_MAGIC 0x1CEB00DAu

typedef unsigned long long ull;

__device__ inline void acc8(const float4& av, const float4& pv, const float4& nv,
                            float& sap, float& san) {
    float d;
    d = av.x - pv.x + EPSC; sap += d * d;
    d = av.y - pv.y + EPSC; sap += d * d;
    d = av.z - pv.z + EPSC; sap += d * d;
    d = av.w - pv.w + EPSC; sap += d * d;
    d = av.x - nv.x + EPSC; san += d * d;
    d = av.y - nv.y + EPSC; san += d * d;
    d = av.z - nv.z + EPSC; san += d * d;
    d = av.w - nv.w + EPSC; san += d * d;
}

// One 256-wide scan step: lane holds j = j0 + lane*4 + s (s=0..3).
__device__ inline void scan4(const int4& lj, const int4& xj, int li, int myidx,
                             int j0, int& pos, int& neg) {
    if (pos < 0) {
        int m = ((lj.x == li && xj.x != myidx) ? 1 : 0)
              | ((lj.y == li && xj.y != myidx) ? 2 : 0)
              | ((lj.z == li && xj.z != myidx) ? 4 : 0)
              | ((lj.w == li && xj.w != myidx) ? 8 : 0);
        unsigned long long b = __ballot(m != 0);
        if (b) {
            int L  = __ffsll(b) - 1;
            int mL = __shfl(m, L, 64);
            pos = j0 + L * 4 + (__ffs(mL) - 1);
        }
    }
    if (neg < 0) {
        int m = ((lj.x != li) ? 1 : 0) | ((lj.y != li) ? 2 : 0)
              | ((lj.z != li) ? 4 : 0) | ((lj.w != li) ? 8 : 0);
        unsigned long long b = __ballot(m != 0);
        if (b) {
            int L  = __ffsll(b) - 1;
            int mL = __shfl(m, L, 64);
            neg = j0 + L * 4 + (__ffs(mL) - 1);
        }
    }
}

// Generic 64-wide per-row scan (B not a multiple of 256).
__device__ inline void mine_row_64(const int* __restrict__ label,
                                   const int* __restrict__ zidx, int B, int lane,
                                   int li, int myidx, int& pos, int& neg) {
    pos = -1; neg = -1;
    for (int j0 = 0; j0 < B && (pos < 0 || neg < 0); j0 += 64) {
        int j = j0 + lane;
        bool inb = j < B;
        int lj = 0, xj = 0;
        if (inb) { lj = label[j]; xj = zidx[j]; }
        unsigned long long pb = __ballot(inb && lj == li && xj != myidx);
        unsigned long long nb = __ballot(inb && lj != li);
        if (pos < 0 && pb) pos = j0 + __ffsll(pb) - 1;
        if (neg < 0 && nb) neg = j0 + __ffsll(nb) - 1;
    }
}

// Cold path: ALL labels identical -> reference relabels rows [0,k) to -1.
__device__ inline void mine_allsame(const int* __restrict__ zidx, int B, int lane,
                                    int i, int myidx, int& pos, int& neg) {
    int k = B / 100; if (k < 2) k = 2;
    int kk = k < B ? k : B;
    int lo, hi;
    if (i < kk) { lo = 0;  hi = kk; neg = (kk < B) ? kk : -1; }
    else        { lo = kk; hi = B;  neg = 0; }
    pos = -1;
    for (int j0 = lo; j0 < hi && pos < 0; j0 += 64) {
        int j = j0 + lane;
        bool ok = (j < hi) && (zidx[j] != myidx);
        unsigned long long b = __ballot(ok);
        if (b) pos = j0 + __ffsll(b) - 1;
    }
}

// Per-row generic (non-1024) distance path, FP order identical to fast path.
__device__ inline void row_generic(const float* __restrict__ z, int i, int pi,
                                   int ni, int C, int lane,
                                   float& lsum, float& lcnt, bool valid) {
    const float4* a = (const float4*)(z + (size_t)i  * C) + lane;
    const float4* p = (const float4*)(z + (size_t)pi * C) + lane;
    const float4* n = (const float4*)(z + (size_t)ni * C) + lane;
    float sap = 0.f, san = 0.f;
    const int nk = C >> 8;
    for (int kk = 0; kk < nk; ++kk)
        acc8(a[kk * 64], p[kk * 64], n[kk * 64], sap, san);
    for (int c = (nk << 8) + lane; c < C; c += 64) {
        float av = z[(size_t)i  * C + c];
        float pv = z[(size_t)pi * C + c];
        float nv = z[(size_t)ni * C + c];
        float d = av - pv + EPSC; sap += d * d;
        d = av - nv + EPSC; san += d * d;
    }
    for (int off = 32; off; off >>= 1) {
        sap += __shfl_xor(sap, off, 64);
        san += __shfl_xor(san, off, 64);
    }
    if (lane == 0 && valid) {
        lsum += fmaxf(sqrtf(sap) - sqrtf(san) + MARGIN, 0.f);
        lcnt += 1.f;
    }
}

// -------- Single kernel: workers (blocks 0..nblk-1) + finisher (block nblk) --
// Workers: identical to the round-5 passing kernel (1 row/wave, 8 waves/block,
// same block->rows map, bit-identical FP trees). Completion protocol: per
// block, relaxed agent atomic-store of the packed partial + RELEASE agent
// atomic-store of a flag — distinct addresses, no RMW, no threadfence (R3's
// +41us came from the single-cacheline ACQ_REL fetch_add funnel + per-block
// fence; neither is present here). Finisher block spins on the flags
// (acquire + s_sleep), then emulates the old 1024-thread final_kernel with
// 512 threads x 2 virtual (lane == t&63, vwave = (t>>6)+8q) so the FP
// reduction tree is bit-identical. Deadlock-free: workers never wait.
__global__ __launch_bounds__(512) void triplet_kernel(
    const float* __restrict__ z, const int* __restrict__ label,
    const int* __restrict__ zidx, int B, int C,
    ull* __restrict__ g_part, unsigned* __restrict__ g_flag,
    float* __restrict__ out, int nblk)
{
    const int lane = threadIdx.x & 63;

    // ---------------- finisher block ----------------
    if ((int)blockIdx.x == nblk) {
        const int t = threadIdx.x;           // 0..511
        for (int f = t; f < nblk; f += 512) {
            while (__hip_atomic_load(&g_flag[f], __ATOMIC_ACQUIRE,
                                     __HIP_MEMORY_SCOPE_AGENT) != FLAG_MAGIC)
                __builtin_amdgcn_s_sleep(1);
        }
        __syncthreads();
        __shared__ float s_s[16], s_c[16];
        for (int q = 0; q < 2; ++q) {
            const int vt = t + 512 * q;      // virtual thread of old 1024-thr kernel
            float s = 0.f, c = 0.f;
            for (int idx = vt; idx < nblk; idx += 1024) {
                ull u = __hip_atomic_load(&g_part[idx], __ATOMIC_RELAXED,
                                          __HIP_MEMORY_SCOPE_AGENT);
                float2 v; __builtin_memcpy(&v, &u, 8);
                s += v.x; c += v.y;
            }
            for (int off = 32; off; off >>= 1) {
                s += __shfl_xor(s, off, 64);
                c += __shfl_xor(c, off, 64);
            }
            if (lane == 0) { s_s[vt >> 6] = s; s_c[vt >> 6] = c; }
        }
        __syncthreads();
        if (t == 0) {
            float ts = 0.f, tc = 0.f;
            for (int w = 0; w < 16; ++w) { ts += s_s[w]; tc += s_c[w]; }
            out[0] = (tc > 0.f) ? ts / tc : 0.f;
        }
        return;
    }

    // ---------------- worker blocks (identical to round 5) ----------------
    const int wave = threadIdx.x >> 6;
    const int i = blockIdx.x * 8 + wave;
    const bool hasR = i < B;
    const bool fast = (C == 1024) && hasR;

    float lsum = 0.f, lcnt = 0.f;

    int li = 0, myidx = 0;
    if (hasR) { li = label[i]; myidx = zidx[i]; }

    // anchor preload — stays in flight across the mining scan
    float4 A0, A1, A2, A3;
    if (fast) {
        const float4* a = (const float4*)(z + (size_t)i * 1024) + lane;
        A0 = a[0]; A1 = a[64]; A2 = a[128]; A3 = a[192];
    }

    // ---- mining (identical per-row logic / first-j semantics) ----
    int pos = -1, neg = -1;
    if (hasR) {
        if ((B & 255) == 0) {
            for (int j0 = 0; j0 < B && (pos < 0 || neg < 0); j0 += 256) {
                const int base = j0 + lane * 4;
                int4 lj = *(const int4*)(label + base);
                int4 xj = *(const int4*)(zidx + base);
                scan4(lj, xj, li, myidx, j0, pos, neg);
            }
        } else {
            mine_row_64(label, zidx, B, lane, li, myidx, pos, neg);
        }
        if (neg < 0)  // no different label anywhere -> all-same cold path
            mine_allsame(zidx, B, lane, i, myidx, pos, neg);
    }

    // ---- distances (identical FP order) ----
    if (fast) {
        const int pi = pos < 0 ? 0 : pos;            // argmax of all-False = 0
        const int ni = neg < 0 ? 0 : neg;
        const float4* p = (const float4*)(z + (size_t)pi * 1024) + lane;
        const float4* n = (const float4*)(z + (size_t)ni * 1024) + lane;
        float4 P0 = p[0], P1 = p[64], P2 = p[128], P3 = p[192];
        float4 N0 = n[0], N1 = n[64], N2 = n[128], N3 = n[192];
        float sap = 0.f, san = 0.f;
        acc8(A0, P0, N0, sap, san); acc8(A1, P1, N1, sap, san);
        acc8(A2, P2, N2, sap, san); acc8(A3, P3, N3, sap, san);
        for (int off = 32; off; off >>= 1) {
            sap += __shfl_xor(sap, off, 64);
            san += __shfl_xor(san, off, 64);
        }
        if (lane == 0 && pos >= 0 && neg >= 0) {
            lsum += fmaxf(sqrtf(sap) - sqrtf(san) + MARGIN, 0.f);
            lcnt += 1.f;
        }
    } else if (hasR) {
        row_generic(z, i, pos < 0 ? 0 : pos, neg < 0 ? 0 : neg,
                    C, lane, lsum, lcnt, pos >= 0 && neg >= 0);
    }

    // ---- block partial: same pair tree as round 5 (bit-exact) ----
    __shared__ float s_sum[8], s_cnt[8];
    if (lane == 0) { s_sum[wave] = lsum; s_cnt[wave] = lcnt; }
    __syncthreads();
    if (threadIdx.x == 0) {
        float bs = 0.f, bc = 0.f;
        for (int w = 0; w < 4; ++w) {
            bs += (s_sum[2 * w] + s_sum[2 * w + 1]);
            bc += (s_cnt[2 * w] + s_cnt[2 * w + 1]);
        }
        float2 v = make_float2(bs, bc);
        ull u; __builtin_memcpy(&u, &v, 8);
        // relaxed partial store (atomic -> coherence point, no L2 writeback
        // needed), then release flag store (orders the partial before it).
        __hip_atomic_store(&g_part[blockIdx.x], u,
                           __ATOMIC_RELAXED, __HIP_MEMORY_SCOPE_AGENT);
        __hip_atomic_store(&g_flag[blockIdx.x], FLAG_MAGIC,
                           __ATOMIC_RELEASE, __HIP_MEMORY_SCOPE_AGENT);
    }
}

extern "C" void kernel_launch(void* const* d_in, const int* in_sizes, int n_in,
                              void* d_out, int out_size, void* d_ws, size_t ws_size,
                              hipStream_t stream) {
    const int*   z_label = (const int*)d_in[0];
    const int*   z_idx   = (const int*)d_in[1];
    const float* z       = (const float*)d_in[2];
    const int B = in_sizes[0];
    const int C = in_sizes[2] / B;
    float* out = (float*)d_out;

    const int nblk = (B + 7) / 8;       // 8 rows per block (1 per wave)
    ull* g_part = (ull*)d_ws;
    // flags after partials, 256B-aligned. Workspace is poisoned by the
    // harness each iteration (the 256MiB fill), so flags never start at
    // FLAG_MAGIC (magic has non-repeating bytes; poison is a byte pattern).
    size_t flag_off = (((size_t)nblk * sizeof(ull)) + 255) & ~(size_t)255;
    unsigned* g_flag = (unsigned*)((char*)d_ws + flag_off);

    triplet_kernel<<<nblk + 1, 512, 0, stream>>>(z, z_label, z_idx, B, C,
                                                 g_part, g_flag, out, nblk);
}

// Round 7
// 85.304 us; speedup vs baseline: 1.1180x; 1.1180x over previous
//
#include <hip/hip_runtime.h>

#define MARGIN 0.2f
#define EPSC 1e-6f

__device__ inline void acc8(const float4& av, const float4& pv, const float4& nv,
                            float& sap, float& san) {
    float d;
    d = av.x - pv.x + EPSC; sap += d * d;
    d = av.y - pv.y + EPSC; sap += d * d;
    d = av.z - pv.z + EPSC; sap += d * d;
    d = av.w - pv.w + EPSC; sap += d * d;
    d = av.x - nv.x + EPSC; san += d * d;
    d = av.y - nv.y + EPSC; san += d * d;
    d = av.z - nv.z + EPSC; san += d * d;
    d = av.w - nv.w + EPSC; san += d * d;
}

// One 256-wide scan step: lane holds j = j0 + lane*4 + s (s=0..3).
__device__ inline void scan4(const int4& lj, const int4& xj, int li, int myidx,
                             int j0, int& pos, int& neg) {
    if (pos < 0) {
        int m = ((lj.x == li && xj.x != myidx) ? 1 : 0)
              | ((lj.y == li && xj.y != myidx) ? 2 : 0)
              | ((lj.z == li && xj.z != myidx) ? 4 : 0)
              | ((lj.w == li && xj.w != myidx) ? 8 : 0);
        unsigned long long b = __ballot(m != 0);
        if (b) {
            int L  = __ffsll(b) - 1;
            int mL = __shfl(m, L, 64);
            pos = j0 + L * 4 + (__ffs(mL) - 1);
        }
    }
    if (neg < 0) {
        int m = ((lj.x != li) ? 1 : 0) | ((lj.y != li) ? 2 : 0)
              | ((lj.z != li) ? 4 : 0) | ((lj.w != li) ? 8 : 0);
        unsigned long long b = __ballot(m != 0);
        if (b) {
            int L  = __ffsll(b) - 1;
            int mL = __shfl(m, L, 64);
            neg = j0 + L * 4 + (__ffs(mL) - 1);
        }
    }
}

// Generic 64-wide per-row scan (B not a multiple of 256).
__device__ inline void mine_row_64(const int* __restrict__ label,
                                   const int* __restrict__ zidx, int B, int lane,
                                   int li, int myidx, int& pos, int& neg) {
    pos = -1; neg = -1;
    for (int j0 = 0; j0 < B && (pos < 0 || neg < 0); j0 += 64) {
        int j = j0 + lane;
        bool inb = j < B;
        int lj = 0, xj = 0;
        if (inb) { lj = label[j]; xj = zidx[j]; }
        unsigned long long pb = __ballot(inb && lj == li && xj != myidx);
        unsigned long long nb = __ballot(inb && lj != li);
        if (pos < 0 && pb) pos = j0 + __ffsll(pb) - 1;
        if (neg < 0 && nb) neg = j0 + __ffsll(nb) - 1;
    }
}

// Cold path: ALL labels identical -> reference relabels rows [0,k) to -1.
__device__ inline void mine_allsame(const int* __restrict__ zidx, int B, int lane,
                                    int i, int myidx, int& pos, int& neg) {
    int k = B / 100; if (k < 2) k = 2;
    int kk = k < B ? k : B;
    int lo, hi;
    if (i < kk) { lo = 0;  hi = kk; neg = (kk < B) ? kk : -1; }
    else        { lo = kk; hi = B;  neg = 0; }
    pos = -1;
    for (int j0 = lo; j0 < hi && pos < 0; j0 += 64) {
        int j = j0 + lane;
        bool ok = (j < hi) && (zidx[j] != myidx);
        unsigned long long b = __ballot(ok);
        if (b) pos = j0 + __ffsll(b) - 1;
    }
}

// Per-row generic (non-1024) distance path, FP order identical to fast path.
__device__ inline void row_generic(const float* __restrict__ z, int i, int pi,
                                   int ni, int C, int lane,
                                   float& lsum, float& lcnt, bool valid) {
    const float4* a = (const float4*)(z + (size_t)i  * C) + lane;
    const float4* p = (const float4*)(z + (size_t)pi * C) + lane;
    const float4* n = (const float4*)(z + (size_t)ni * C) + lane;
    float sap = 0.f, san = 0.f;
    const int nk = C >> 8;
    for (int kk = 0; kk < nk; ++kk)
        acc8(a[kk * 64], p[kk * 64], n[kk * 64], sap, san);
    for (int c = (nk << 8) + lane; c < C; c += 64) {
        float av = z[(size_t)i  * C + c];
        float pv = z[(size_t)pi * C + c];
        float nv = z[(size_t)ni * C + c];
        float d = av - pv + EPSC; sap += d * d;
        d = av - nv + EPSC; san += d * d;
    }
    for (int off = 32; off; off >>= 1) {
        sap += __shfl_xor(sap, off, 64);
        san += __shfl_xor(san, off, 64);
    }
    if (lane == 0 && valid) {
        lsum += fmaxf(sqrtf(sap) - sqrtf(san) + MARGIN, 0.f);
        lcnt += 1.f;
    }
}

// -------- Kernel 1: fused mine + distances, ONE row per wave ---------------
// 512 threads = 8 waves; block covers rows [blockIdx*8, blockIdx*8+8).
// Per-wave data is 12 float4 (48 VGPRs) so the gathers genuinely stay in
// flight (round 3 showed VGPR_Count=48 serialized the 24-float4 scheme), and
// 8 waves/block doubles TLP over the latency chains. Anchor loads issue
// before the mining scan; their latency hides under it.
// NOTE (R3/R6 lessons): do NOT replace the final_kernel dispatch with an
// in-kernel completion protocol. Measured: ACQ_REL counter funnel +41us;
// release-flags + finisher-block acquire-spin +12us. The kernel boundary is
// the cheapest device-wide barrier on 8 XCDs.
__global__ __launch_bounds__(512) void triplet_kernel(
    const float* __restrict__ z, const int* __restrict__ label,
    const int* __restrict__ zidx, int B, int C, float2* __restrict__ g_part)
{
    const int wave = threadIdx.x >> 6;
    const int lane = threadIdx.x & 63;
    const int i = blockIdx.x * 8 + wave;
    const bool hasR = i < B;
    const bool fast = (C == 1024) && hasR;

    float lsum = 0.f, lcnt = 0.f;

    int li = 0, myidx = 0;
    if (hasR) { li = label[i]; myidx = zidx[i]; }

    // anchor preload — stays in flight across the mining scan
    float4 A0, A1, A2, A3;
    if (fast) {
        const float4* a = (const float4*)(z + (size_t)i * 1024) + lane;
        A0 = a[0]; A1 = a[64]; A2 = a[128]; A3 = a[192];
    }

    // ---- mining (identical per-row logic / first-j semantics) ----
    int pos = -1, neg = -1;
    if (hasR) {
        if ((B & 255) == 0) {
            for (int j0 = 0; j0 < B && (pos < 0 || neg < 0); j0 += 256) {
                const int base = j0 + lane * 4;
                int4 lj = *(const int4*)(label + base);
                int4 xj = *(const int4*)(zidx + base);
                scan4(lj, xj, li, myidx, j0, pos, neg);
            }
        } else {
            mine_row_64(label, zidx, B, lane, li, myidx, pos, neg);
        }
        if (neg < 0)  // no different label anywhere -> all-same cold path
            mine_allsame(zidx, B, lane, i, myidx, pos, neg);
    }

    // ---- distances (identical FP order) ----
    if (fast) {
        const int pi = pos < 0 ? 0 : pos;            // argmax of all-False = 0
        const int ni = neg < 0 ? 0 : neg;
        const float4* p = (const float4*)(z + (size_t)pi * 1024) + lane;
        const float4* n = (const float4*)(z + (size_t)ni * 1024) + lane;
        float4 P0 = p[0], P1 = p[64], P2 = p[128], P3 = p[192];
        float4 N0 = n[0], N1 = n[64], N2 = n[128], N3 = n[192];
        float sap = 0.f, san = 0.f;
        acc8(A0, P0, N0, sap, san); acc8(A1, P1, N1, sap, san);
        acc8(A2, P2, N2, sap, san); acc8(A3, P3, N3, sap, san);
        for (int off = 32; off; off >>= 1) {
            sap += __shfl_xor(sap, off, 64);
            san += __shfl_xor(san, off, 64);
        }
        if (lane == 0 && pos >= 0 && neg >= 0) {
            lsum += fmaxf(sqrtf(sap) - sqrtf(san) + MARGIN, 0.f);
            lcnt += 1.f;
        }
    } else if (hasR) {
        row_generic(z, i, pos < 0 ? 0 : pos, neg < 0 ? 0 : neg,
                    C, lane, lsum, lcnt, pos >= 0 && neg >= 0);
    }

    // ---- block partial: replicate the old 4-wave pair tree bit-exactly.
    __shared__ float s_sum[8], s_cnt[8];
    if (lane == 0) { s_sum[wave] = lsum; s_cnt[wave] = lcnt; }
    __syncthreads();
    if (threadIdx.x == 0) {
        float bs = 0.f, bc = 0.f;
        for (int w = 0; w < 4; ++w) {
            bs += (s_sum[2 * w] + s_sum[2 * w + 1]);
            bc += (s_cnt[2 * w] + s_cnt[2 * w + 1]);
        }
        g_part[blockIdx.x] = make_float2(bs, bc);   // plain store; visibility
    }                                               // via kernel boundary
}

// -------- Kernel 2: reduce partials, write loss (unchanged, bit-exact) ------
__global__ __launch_bounds__(1024) void final_kernel(
    const float2* __restrict__ g_part, int nb, float* __restrict__ out)
{
    const int t = threadIdx.x;
    float s = 0.f, c = 0.f;
    for (int idx = t; idx < nb; idx += blockDim.x) {
        float2 v = g_part[idx];
        s += v.x; c += v.y;
    }
    for (int off = 32; off; off >>= 1) {
        s += __shfl_xor(s, off, 64);
        c += __shfl_xor(c, off, 64);
    }
    __shared__ float s_s[16], s_c[16];
    const int wave = t >> 6, lane = t & 63;
    if (lane == 0) { s_s[wave] = s; s_c[wave] = c; }
    __syncthreads();
    if (t == 0) {
        float ts = 0.f, tc = 0.f;
        const int nw = blockDim.x >> 6;
        for (int w = 0; w < nw; ++w) { ts += s_s[w]; tc += s_c[w]; }
        out[0] = (tc > 0.f) ? ts / tc : 0.f;
    }
}

extern "C" void kernel_launch(void* const* d_in, const int* in_sizes, int n_in,
                              void* d_out, int out_size, void* d_ws, size_t ws_size,
                              hipStream_t stream) {
    const int*   z_label = (const int*)d_in[0];
    const int*   z_idx   = (const int*)d_in[1];
    const float* z       = (const float*)d_in[2];
    const int B = in_sizes[0];
    const int C = in_sizes[2] / B;
    float* out = (float*)d_out;

    const int nblk = (B + 7) / 8;       // 8 rows per block (1 per wave)
    float2* g_part = (float2*)d_ws;

    triplet_kernel<<<nblk, 512, 0, stream>>>(z, z_label, z_idx, B, C, g_part);
    final_kernel<<<1, 1024, 0, stream>>>(g_part, nblk, out);
}